// Round 9
// baseline (177.989 us; speedup 1.0000x reference)
//
#include <hip/hip_runtime.h>
#include <hip/hip_fp16.h>

// GCN 2-layer, pull-based CSR gather, fp16 dense intermediates.
// R22 = R21 with the binB scale-tail index bug fixed (R21 scaled only 64 of
// 256 rows/bucket -> absmax 1.3). Each wave now covers rows r = w, w+4, ...,
// 252 (64 rows x 4 waves = 256).
// R21 = R18 (best verified, 161.8us) + scale_k folded into binB_k:
//   binB blocks already own a 256-node bucket and compute its degrees;
//   after the sort scatter they scale the same 256 hs1 rows in-place by
//   dinv (wave-per-row, 64 x half2 = 256B coalesced; dinv passed via LDS).
//   -1 launch, scale traffic (25.6MB R+W) overlapped into the
//   under-occupied (196-block) latency-bound sort kernel.
// Everything else identical to R18: k1 = gemm1 ∪ binA, 2048-key src-tiled
// counting sort, quarter-wave g1mm (gather1+gemm2), eighth-wave gather2.
// N <= 65536.

typedef _Float16 half_t;
typedef _Float16 half2_t __attribute__((ext_vector_type(2)));
typedef _Float16 f16x4 __attribute__((ext_vector_type(4)));
typedef _Float16 f16x8 __attribute__((ext_vector_type(8)));
typedef float f32x4 __attribute__((ext_vector_type(4)));

#define BKT_CAP 8192   // per-bucket ebuf capacity (expected load 4096, sigma 64)

// inclusive block scan over 256 threads (4 waves); caller provides 4-int LDS
__device__ __forceinline__ int incl_scan256(int v, volatile int* wsum) {
    int t = threadIdx.x, lane = t & 63, w = t >> 6;
#pragma unroll
    for (int off = 1; off < 64; off <<= 1) {
        int u = __shfl_up(v, off);
        if (lane >= off) v += u;
    }
    if (lane == 63) wsum[w] = v;
    __syncthreads();
    int add = 0;
#pragma unroll
    for (int i = 0; i < 3; ++i)
        if (i < w) add += wsum[i];
    return v + add;
}

// ---------------- gemm1: 128x128 tile via f16 MFMA ----------------
// MFMA 16x16x32 layouts (gfx950, HW-verified):
//   A-frag: lane holds A[m=lane&15][k=(lane>>4)*8+j]
//   B-frag: lane holds B[k=(lane>>4)*8+j][n=lane&15]
//   C/D   : col=lane&15, row=(lane>>4)*4+reg

__device__ __forceinline__ void gemm1_mfma(const float* __restrict__ x,
                                           const float* __restrict__ W,
                                           half_t* __restrict__ C, int M, int r0) {
    __shared__ _Float16 Wt[128][136];          // [n][k], rows 272B (b128-aligned)
    __shared__ _Float16 Xs[128][40];           // [m][k-chunk], rows 80B
    const int t = threadIdx.x;

    // stage W^T fp16: coalesced reads along n, b64 writes along k
    {
        const int n = t & 127;
#pragma unroll
        for (int kb = (t >> 7) * 4; kb < 128; kb += 8) {
            f16x4 hv;
            hv[0] = (_Float16)W[(size_t)(kb + 0) * 128 + n];
            hv[1] = (_Float16)W[(size_t)(kb + 1) * 128 + n];
            hv[2] = (_Float16)W[(size_t)(kb + 2) * 128 + n];
            hv[3] = (_Float16)W[(size_t)(kb + 3) * 128 + n];
            *(f16x4*)&Wt[n][kb] = hv;
        }
    }

    const int w = t >> 6, lane = t & 63;
    const int m = lane & 15, q = lane >> 4;

    // Xs staging coords: 16 floats (one row-half-chunk) per thread per kc
    const int sr = t >> 1;               // 0..127 tile row
    const int sk = (t & 1) * 16;         // 0 or 16 within 32-k chunk
    const int srow = (r0 + sr < M) ? (r0 + sr) : (M - 1);

    f32x4 acc[2][8];
#pragma unroll
    for (int rt = 0; rt < 2; ++rt)
#pragma unroll
        for (int ct = 0; ct < 8; ++ct)
#pragma unroll
            for (int r = 0; r < 4; ++r) acc[rt][ct][r] = 0.f;

#pragma unroll
    for (int kc = 0; kc < 4; ++kc) {
        // coalesced global loads issued before the barrier (overlap prev MFMAs)
        const float* xp = &x[(size_t)srow * 128 + kc * 32 + sk];
        float4 v0 = *(const float4*)xp;
        float4 v1 = *(const float4*)(xp + 4);
        float4 v2 = *(const float4*)(xp + 8);
        float4 v3 = *(const float4*)(xp + 12);
        __syncthreads();                 // prev iter's Xs reads done (&& Wt staged)
        f16x8 s0, s1;
        s0[0] = (_Float16)v0.x; s0[1] = (_Float16)v0.y;
        s0[2] = (_Float16)v0.z; s0[3] = (_Float16)v0.w;
        s0[4] = (_Float16)v1.x; s0[5] = (_Float16)v1.y;
        s0[6] = (_Float16)v1.z; s0[7] = (_Float16)v1.w;
        s1[0] = (_Float16)v2.x; s1[1] = (_Float16)v2.y;
        s1[2] = (_Float16)v2.z; s1[3] = (_Float16)v2.w;
        s1[4] = (_Float16)v3.x; s1[5] = (_Float16)v3.y;
        s1[6] = (_Float16)v3.z; s1[7] = (_Float16)v3.w;
        *(f16x8*)&Xs[sr][sk] = s0;
        *(f16x8*)&Xs[sr][sk + 8] = s1;
        __syncthreads();

        const int k0 = q * 8;
        f16x8 a0 = *(const f16x8*)&Xs[(w * 2 + 0) * 16 + m][k0];
        f16x8 a1 = *(const f16x8*)&Xs[(w * 2 + 1) * 16 + m][k0];
        const int kw = kc * 32 + k0;
#pragma unroll
        for (int ct = 0; ct < 8; ++ct) {
            f16x8 b = *(const f16x8*)&Wt[ct * 16 + m][kw];
            acc[0][ct] = __builtin_amdgcn_mfma_f32_16x16x32_f16(a0, b, acc[0][ct], 0, 0, 0);
            acc[1][ct] = __builtin_amdgcn_mfma_f32_16x16x32_f16(a1, b, acc[1][ct], 0, 0, 0);
        }
    }

#pragma unroll
    for (int rt = 0; rt < 2; ++rt)
#pragma unroll
        for (int ct = 0; ct < 8; ++ct)
#pragma unroll
            for (int r = 0; r < 4; ++r) {
                int row = r0 + (w * 2 + rt) * 16 + q * 4 + r;
                if (row < M)
                    C[(size_t)row * 128 + ct * 16 + m] = (half_t)acc[rt][ct][r];
            }
}

// ---------------- k1: gemm1 blocks, then pass-A binning blocks --------------

__launch_bounds__(256)
__global__ void gemm_binA_k(const float* __restrict__ A, const float* __restrict__ W,
                            half_t* __restrict__ C, int M, int Gg1,
                            const int* __restrict__ esrc, const int* __restrict__ edst,
                            int* __restrict__ bucket_cnt, unsigned int* __restrict__ ebuf,
                            int E) {
    int b = blockIdx.x;
    if (b < Gg1) {
        gemm1_mfma(A, W, C, M, b * 128);
        return;
    }
    __shared__ int cntA[256];
    __shared__ int curA[256];
    __shared__ int deltaA[256];
    __shared__ int wsumA[4];

    const int t = threadIdx.x;
    const int base = (b - Gg1) * 4096;
    int ls[16], ld[16];

    cntA[t] = 0;
    __syncthreads();
#pragma unroll
    for (int j = 0; j < 16; ++j) {
        int idx = base + j * 256 + t;
        if (idx < E) {
            ls[j] = esrc[idx];
            ld[j] = edst[idx];
            atomicAdd(&cntA[ld[j] >> 8], 1);
        } else {
            ls[j] = -1;
            ld[j] = 0;
        }
    }
    __syncthreads();

    int c = cntA[t];
    int incl = incl_scan256(c, wsumA);      // contains a __syncthreads
    int excl = incl - c;
    int gbase = atomicAdd(&bucket_cnt[t], c);       // offset within bucket segment
    deltaA[t] = t * BKT_CAP + gbase - excl;         // absolute = seg base + offset
    curA[t] = excl;
    __syncthreads();

#pragma unroll
    for (int j = 0; j < 16; ++j) {
        if (ls[j] >= 0) {
            int bkt = ld[j] >> 8;
            int p = atomicAdd(&curA[bkt], 1);
            ebuf[deltaA[bkt] + p] = ((unsigned int)ls[j] << 8) | ((unsigned int)ld[j] & 255u);
        }
    }
}

// ---------------- k2 (pass B): counting sort -> rs/dinv/ssrc, + hs1 scale ---
// Sort key = ((dst&255)<<3) | (src>>13): per-node adjacency grouped by
// 8192-node source tile (R18 ordering). Tail: scale this bucket's 256 hs1
// rows in-place by dinv (folds the old scale_k into this kernel).

__launch_bounds__(256)
__global__ void binB_k(const int* __restrict__ bucket_cnt,
                       const unsigned int* __restrict__ ebuf,
                       unsigned short* __restrict__ ssrc,
                       int* __restrict__ rs, float* __restrict__ dinv,
                       half_t* __restrict__ hs1,
                       int N, int NB) {
    __shared__ int cnt[2048];                  // per (dstlow, tile) counters
    __shared__ int pre[256];
    __shared__ float dinvs[256];               // this bucket's dinv (for scale tail)
    __shared__ int wsum1[4];
    __shared__ int wsum2[4];

    const int t = threadIdx.x;
    const int b = blockIdx.x;

    int v = (t < NB) ? bucket_cnt[t] : 0;
    int inclb = incl_scan256(v, wsum1);
    pre[t] = inclb;
    __syncthreads();
    const int gb = (b > 0) ? pre[b - 1] : 0;
    const int sz = pre[b] - gb;
    const unsigned int* seg = ebuf + (size_t)b * BKT_CAP;

#pragma unroll
    for (int i = 0; i < 8; ++i) cnt[t + i * 256] = 0;
    __syncthreads();
    for (int i = t; i < sz; i += 256) {
        unsigned int pk = seg[i];
        int key = ((pk & 255u) << 3) | ((pk >> 8) >> 13);   // (dstlow, srctile)
        atomicAdd(&cnt[key], 1);
    }
    __syncthreads();

    // thread t owns keys 8t..8t+7 (= node dstlow t, all 8 tiles)
    int c8[8];
    int s = 0;
#pragma unroll
    for (int j = 0; j < 8; ++j) { c8[j] = cnt[t * 8 + j]; s += c8[j]; }
    int incl = incl_scan256(s, wsum2);         // contains a __syncthreads
    int excl = incl - s;
    int node = b * 256 + t;
    float dval = rsqrtf(1.0f + (float)s);
    dinvs[t] = dval;
    if (node < N) {
        rs[node] = gb + excl;
        dinv[node] = dval;
    }
    int run = excl;
#pragma unroll
    for (int j = 0; j < 8; ++j) { int cv = c8[j]; cnt[t * 8 + j] = run; run += cv; }
    __syncthreads();

    for (int i = t; i < sz; i += 256) {
        unsigned int pk = seg[i];
        int key = ((pk & 255u) << 3) | ((pk >> 8) >> 13);
        int p = atomicAdd(&cnt[key], 1);
        ssrc[gb + p] = (unsigned short)(pk >> 8);
    }

    // tail: scale this bucket's hs1 rows in-place (wave-per-row, 256B coalesced)
    // wave w covers rows r = w, w+4, ..., 252 (64 rows x 4 waves = 256). [R21 bug fix]
    {
        const int w = t >> 6, lane = t & 63;
#pragma unroll 1
        for (int r = w; r < 256; r += 4) {
            int row = b * 256 + r;
            if (row < N) {
                float sc = dinvs[r];
                half2_t* p2 = (half2_t*)&hs1[(size_t)row * 128 + 2 * lane];
                half2_t hv = *p2;
                hv.x = (half_t)((float)hv.x * sc);
                hv.y = (half_t)((float)hv.y * sc);
                *p2 = hv;
            }
        }
    }
}

// ---------------- g1mm: fused gather1 (quarter-wave/node) + gemm2 -----------
// hs rows pre-scaled by dinv (binB tail), so the aggregate is a pure sum:
// g1_row = relu(dv * (sum_in hs[s] + hs[node]) + b1).
// Per block: 16 nodes; each wave owns 4 concurrent nodes (one per 16-lane
// quarter, f16x8/lane = 128 dims). Rows -> LDS g1s, then M=16 MFMA with
// W2^T; epilogue scales by dinv (pre-scaling hs2 for gather2).

__launch_bounds__(256)
__global__ void g1mm_k(const half_t* __restrict__ hs,
                       const unsigned short* __restrict__ ssrc,
                       const int* __restrict__ rs,
                       const float* __restrict__ dinv,
                       const float* __restrict__ b1,
                       const float* __restrict__ W2,
                       half_t* __restrict__ o, int N, int E) {
    __shared__ _Float16 Wt[64][136];           // [n][k], W2^T fp16
    __shared__ _Float16 g1s[16][136];          // gathered+activated rows
    const int t = threadIdx.x;

    // stage W2^T fp16: coalesced reads along n, b64 writes along k
    {
        const int n = t & 63;
#pragma unroll
        for (int kb = (t >> 6) * 4; kb < 128; kb += 16) {
            f16x4 hv;
            hv[0] = (_Float16)W2[(size_t)(kb + 0) * 64 + n];
            hv[1] = (_Float16)W2[(size_t)(kb + 1) * 64 + n];
            hv[2] = (_Float16)W2[(size_t)(kb + 2) * 64 + n];
            hv[3] = (_Float16)W2[(size_t)(kb + 3) * 64 + n];
            *(f16x4*)&Wt[n][kb] = hv;
        }
    }

    const int w = t >> 6, lane = t & 63;
    const int qd = lane >> 4, l4 = lane & 15;
    const int nb = blockIdx.x * 16;
    const half_t* hp = hs + 8 * l4;            // dims 8*l4 .. 8*l4+7
    const int sl = qd * 16;                    // shfl base for this quarter

    int node = nb + w * 4 + qd;                // this quarter's node
    int vnode = (node < N) ? node : (N - 1);
    int start = rs[vnode];
    int end = (vnode + 1 < N) ? rs[vnode + 1] : E;
    float dv = dinv[vnode];

    f16x8 sv = *(const f16x8*)&hp[(size_t)vnode * 128];   // self (pre-scaled)
    float acc[8];
#pragma unroll
    for (int j = 0; j < 8; ++j) acc[j] = (float)sv[j];

    for (int base = start; base < end; base += 16) {
        int n = end - base;
        if (n > 16) n = 16;
        int gi = (base + l4 < end) ? (base + l4) : base;
        int idx = (int)ssrc[gi];
        int e = 0;
        for (; e + 4 <= n; e += 4) {           // 4 edges in flight per quarter
            int s0 = __shfl(idx, sl + e + 0);
            int s1 = __shfl(idx, sl + e + 1);
            int s2 = __shfl(idx, sl + e + 2);
            int s3 = __shfl(idx, sl + e + 3);
            f16x8 x0 = *(const f16x8*)&hp[(size_t)s0 * 128];
            f16x8 x1 = *(const f16x8*)&hp[(size_t)s1 * 128];
            f16x8 x2 = *(const f16x8*)&hp[(size_t)s2 * 128];
            f16x8 x3 = *(const f16x8*)&hp[(size_t)s3 * 128];
#pragma unroll
            for (int j = 0; j < 8; ++j) acc[j] += (float)x0[j];
#pragma unroll
            for (int j = 0; j < 8; ++j) acc[j] += (float)x1[j];
#pragma unroll
            for (int j = 0; j < 8; ++j) acc[j] += (float)x2[j];
#pragma unroll
            for (int j = 0; j < 8; ++j) acc[j] += (float)x3[j];
        }
        for (; e < n; ++e) {
            int s0 = __shfl(idx, sl + e);
            f16x8 x0 = *(const f16x8*)&hp[(size_t)s0 * 128];
#pragma unroll
            for (int j = 0; j < 8; ++j) acc[j] += (float)x0[j];
        }
    }

    // epilogue: relu(acc*dv + b1) -> LDS row (each quarter owns a full row)
    {
        float4 ba = *(const float4*)&b1[8 * l4];
        float4 bb = *(const float4*)&b1[8 * l4 + 4];
        f16x8 hv;
        hv[0] = (half_t)fmaxf(acc[0] * dv + ba.x, 0.f);
        hv[1] = (half_t)fmaxf(acc[1] * dv + ba.y, 0.f);
        hv[2] = (half_t)fmaxf(acc[2] * dv + ba.z, 0.f);
        hv[3] = (half_t)fmaxf(acc[3] * dv + ba.w, 0.f);
        hv[4] = (half_t)fmaxf(acc[4] * dv + bb.x, 0.f);
        hv[5] = (half_t)fmaxf(acc[5] * dv + bb.y, 0.f);
        hv[6] = (half_t)fmaxf(acc[6] * dv + bb.z, 0.f);
        hv[7] = (half_t)fmaxf(acc[7] * dv + bb.w, 0.f);
        *(f16x8*)&g1s[w * 4 + qd][8 * l4] = hv;
    }
    __syncthreads();

    // M=16 x N=64 x K=128 MFMA; wave w owns output cols w*16..w*16+15
    const int m = lane & 15, q = lane >> 4;
    f32x4 acc2;
#pragma unroll
    for (int r = 0; r < 4; ++r) acc2[r] = 0.f;
#pragma unroll
    for (int kc = 0; kc < 4; ++kc) {
        const int k0 = kc * 32 + q * 8;
        f16x8 a = *(const f16x8*)&g1s[m][k0];
        f16x8 b = *(const f16x8*)&Wt[w * 16 + m][k0];
        acc2 = __builtin_amdgcn_mfma_f32_16x16x32_f16(a, b, acc2, 0, 0, 0);
    }
#pragma unroll
    for (int r = 0; r < 4; ++r) {
        int row = nb + q * 4 + r;
        if (row < N) {
            float s = dinv[row];
            o[(size_t)row * 64 + w * 16 + m] = (half_t)(acc2[r] * s);
        }
    }
}

// ---------------- gather2: 64-dim, eighth-wave per node, fp32 out -----------

__global__ void gather2_k(const half_t* __restrict__ hs,
                          const unsigned short* __restrict__ ssrc,
                          const int* __restrict__ rs,
                          const float* __restrict__ dinv,
                          const float* __restrict__ bias,
                          float* __restrict__ o, int N, int E) {
    int wid = (int)((blockIdx.x * blockDim.x + threadIdx.x) >> 6);
    int lane = threadIdx.x & 63;
    const int sg = lane >> 3, l3 = lane & 7;
    int rnode = wid * 8 + sg;                  // this eighth's node
    int node = (rnode < N) ? rnode : (N - 1);

    int start = rs[node];
    int end = (node + 1 < N) ? rs[node + 1] : E;
    float dv = dinv[node];
    const int sl = sg * 8;

    const half_t* hp = hs + 8 * l3;            // dims 8*l3 .. 8*l3+7
    f16x8 sv = *(const f16x8*)&hp[(size_t)node * 64];
    float acc[8];
#pragma unroll
    for (int j = 0; j < 8; ++j) acc[j] = (float)sv[j];   // self (pre-scaled)

    for (int base = start; base < end; base += 8) {
        int n = end - base;
        if (n > 8) n = 8;
        int gi = (base + l3 < end) ? (base + l3) : base;
        int idx = (int)ssrc[gi];
        int e = 0;
        for (; e + 4 <= n; e += 4) {           // 4 edges in flight per eighth
            int s0 = __shfl(idx, sl + e + 0);
            int s1 = __shfl(idx, sl + e + 1);
            int s2 = __shfl(idx, sl + e + 2);
            int s3 = __shfl(idx, sl + e + 3);
            f16x8 a0 = *(const f16x8*)&hp[(size_t)s0 * 64];
            f16x8 a1 = *(const f16x8*)&hp[(size_t)s1 * 64];
            f16x8 a2 = *(const f16x8*)&hp[(size_t)s2 * 64];
            f16x8 a3 = *(const f16x8*)&hp[(size_t)s3 * 64];
#pragma unroll
            for (int j = 0; j < 8; ++j) acc[j] += (float)a0[j];
#pragma unroll
            for (int j = 0; j < 8; ++j) acc[j] += (float)a1[j];
#pragma unroll
            for (int j = 0; j < 8; ++j) acc[j] += (float)a2[j];
#pragma unroll
            for (int j = 0; j < 8; ++j) acc[j] += (float)a3[j];
        }
        for (; e < n; ++e) {
            int s0 = __shfl(idx, sl + e);
            f16x8 a0 = *(const f16x8*)&hp[(size_t)s0 * 64];
#pragma unroll
            for (int j = 0; j < 8; ++j) acc[j] += (float)a0[j];
        }
    }
    if (rnode < N) {
        float4 b0 = *(const float4*)&bias[8 * l3];
        float4 b1v = *(const float4*)&bias[8 * l3 + 4];
        float4 o0, o1;
        o0.x = acc[0] * dv + b0.x;
        o0.y = acc[1] * dv + b0.y;
        o0.z = acc[2] * dv + b0.z;
        o0.w = acc[3] * dv + b0.w;
        o1.x = acc[4] * dv + b1v.x;
        o1.y = acc[5] * dv + b1v.y;
        o1.z = acc[6] * dv + b1v.z;
        o1.w = acc[7] * dv + b1v.w;
        *(float4*)&o[(size_t)rnode * 64 + 8 * l3] = o0;
        *(float4*)&o[(size_t)rnode * 64 + 8 * l3 + 4] = o1;
    }
}

// ---------------- launcher ----------------

extern "C" void kernel_launch(void* const* d_in, const int* in_sizes, int n_in,
                              void* d_out, int out_size, void* d_ws, size_t ws_size,
                              hipStream_t stream) {
    const float* x  = (const float*)d_in[0];
    const int*   ei = (const int*)d_in[1];
    const float* W1 = (const float*)d_in[2];
    const float* b1 = (const float*)d_in[3];
    const float* W2 = (const float*)d_in[4];
    const float* b2 = (const float*)d_in[5];
    float* out = (float*)d_out;

    const int N = in_sizes[0] / 128;
    const int E = in_sizes[1] / 2;
    const int* esrc = ei;
    const int* edst = ei + E;

    const int NB  = (N + 255) / 256;          // buckets (<=256 requires N<=65536)
    const int Gg1 = (N + 127) / 128;
    const int GA  = (E + 4095) / 4096;

    // workspace layout
    int* bucket_cnt = (int*)d_ws;                             // 256
    unsigned int* ebuf = (unsigned int*)(bucket_cnt + 256);   // NB*BKT_CAP packed edges
    unsigned short* ssrc = (unsigned short*)(ebuf + (size_t)NB * BKT_CAP); // E uint16
    int* rs = (int*)(ssrc + ((E + 1) & ~1));                  // N
    float* dinv = (float*)(rs + N);                           // N
    half_t* hs1 = (half_t*)(dinv + N);                        // N*128 fp16 (scaled in binB)
    half_t* hs2 = hs1 + (size_t)N * 128;                      // N*64 fp16 (pre-scaled)

    hipMemsetAsync(bucket_cnt, 0, 256 * 4, stream);

    // k1: gemm1 (unscaled fp16 h1) ∪ pass-A edge binning
    hipLaunchKernelGGL(gemm_binA_k, dim3(Gg1 + GA), dim3(256), 0, stream,
                       x, W1, hs1, N, Gg1, esrc, edst, bucket_cnt, ebuf, E);
    // k2: counting sort (dst, src-tile) -> rs, dinv, ssrc; + hs1 *= dinv tail
    hipLaunchKernelGGL(binB_k, dim3(NB), dim3(256), 0, stream,
                       bucket_cnt, ebuf, ssrc, rs, dinv, hs1, N, NB);
    // fused layer-1 aggregate + layer-2 linear (writes pre-scaled hs2)
    hipLaunchKernelGGL(g1mm_k, dim3((N + 15) / 16), dim3(256), 0, stream,
                       hs1, ssrc, rs, dinv, b1, W2, hs2, N, E);
    // layer-2 aggregate
    hipLaunchKernelGGL(gather2_k, dim3((N + 31) / 32), dim3(256), 0, stream,
                       hs2, ssrc, rs, dinv, b2, out, N, E);
}

// Round 10
// 170.710 us; speedup vs baseline: 1.0426x; 1.0426x over previous
//
#include <hip/hip_runtime.h>
#include <hip/hip_fp16.h>

// GCN 2-layer, pull-based CSR gather, fp16 dense intermediates.
// R23 = R22 with the binB scale-tail latency bug fixed: R22 used
// `#pragma unroll 1` + per-row load->store, i.e. 64 serial ~600cy LLC
// round-trips per block (~16us exposed at 196 blocks - exactly the observed
// regression vs R18). Tail now processes 8 rows/batch with all 8 loads
// hoisted (8 outstanding/wave, 32/block) -> ~2us.
// R22/R21 = R18 (best verified, 161.8us) + scale_k folded into binB_k
// (-1 launch, 25.6MB R+W overlapped into the latency-bound sort kernel).
// Everything else identical to R18: k1 = gemm1 ∪ binA, 2048-key src-tiled
// counting sort, quarter-wave g1mm (gather1+gemm2), eighth-wave gather2.
// N <= 65536.

typedef _Float16 half_t;
typedef _Float16 half2_t __attribute__((ext_vector_type(2)));
typedef _Float16 f16x4 __attribute__((ext_vector_type(4)));
typedef _Float16 f16x8 __attribute__((ext_vector_type(8)));
typedef float f32x4 __attribute__((ext_vector_type(4)));

#define BKT_CAP 8192   // per-bucket ebuf capacity (expected load 4096, sigma 64)

// inclusive block scan over 256 threads (4 waves); caller provides 4-int LDS
__device__ __forceinline__ int incl_scan256(int v, volatile int* wsum) {
    int t = threadIdx.x, lane = t & 63, w = t >> 6;
#pragma unroll
    for (int off = 1; off < 64; off <<= 1) {
        int u = __shfl_up(v, off);
        if (lane >= off) v += u;
    }
    if (lane == 63) wsum[w] = v;
    __syncthreads();
    int add = 0;
#pragma unroll
    for (int i = 0; i < 3; ++i)
        if (i < w) add += wsum[i];
    return v + add;
}

// ---------------- gemm1: 128x128 tile via f16 MFMA ----------------
// MFMA 16x16x32 layouts (gfx950, HW-verified):
//   A-frag: lane holds A[m=lane&15][k=(lane>>4)*8+j]
//   B-frag: lane holds B[k=(lane>>4)*8+j][n=lane&15]
//   C/D   : col=lane&15, row=(lane>>4)*4+reg

__device__ __forceinline__ void gemm1_mfma(const float* __restrict__ x,
                                           const float* __restrict__ W,
                                           half_t* __restrict__ C, int M, int r0) {
    __shared__ _Float16 Wt[128][136];          // [n][k], rows 272B (b128-aligned)
    __shared__ _Float16 Xs[128][40];           // [m][k-chunk], rows 80B
    const int t = threadIdx.x;

    // stage W^T fp16: coalesced reads along n, b64 writes along k
    {
        const int n = t & 127;
#pragma unroll
        for (int kb = (t >> 7) * 4; kb < 128; kb += 8) {
            f16x4 hv;
            hv[0] = (_Float16)W[(size_t)(kb + 0) * 128 + n];
            hv[1] = (_Float16)W[(size_t)(kb + 1) * 128 + n];
            hv[2] = (_Float16)W[(size_t)(kb + 2) * 128 + n];
            hv[3] = (_Float16)W[(size_t)(kb + 3) * 128 + n];
            *(f16x4*)&Wt[n][kb] = hv;
        }
    }

    const int w = t >> 6, lane = t & 63;
    const int m = lane & 15, q = lane >> 4;

    // Xs staging coords: 16 floats (one row-half-chunk) per thread per kc
    const int sr = t >> 1;               // 0..127 tile row
    const int sk = (t & 1) * 16;         // 0 or 16 within 32-k chunk
    const int srow = (r0 + sr < M) ? (r0 + sr) : (M - 1);

    f32x4 acc[2][8];
#pragma unroll
    for (int rt = 0; rt < 2; ++rt)
#pragma unroll
        for (int ct = 0; ct < 8; ++ct)
#pragma unroll
            for (int r = 0; r < 4; ++r) acc[rt][ct][r] = 0.f;

#pragma unroll
    for (int kc = 0; kc < 4; ++kc) {
        // coalesced global loads issued before the barrier (overlap prev MFMAs)
        const float* xp = &x[(size_t)srow * 128 + kc * 32 + sk];
        float4 v0 = *(const float4*)xp;
        float4 v1 = *(const float4*)(xp + 4);
        float4 v2 = *(const float4*)(xp + 8);
        float4 v3 = *(const float4*)(xp + 12);
        __syncthreads();                 // prev iter's Xs reads done (&& Wt staged)
        f16x8 s0, s1;
        s0[0] = (_Float16)v0.x; s0[1] = (_Float16)v0.y;
        s0[2] = (_Float16)v0.z; s0[3] = (_Float16)v0.w;
        s0[4] = (_Float16)v1.x; s0[5] = (_Float16)v1.y;
        s0[6] = (_Float16)v1.z; s0[7] = (_Float16)v1.w;
        s1[0] = (_Float16)v2.x; s1[1] = (_Float16)v2.y;
        s1[2] = (_Float16)v2.z; s1[3] = (_Float16)v2.w;
        s1[4] = (_Float16)v3.x; s1[5] = (_Float16)v3.y;
        s1[6] = (_Float16)v3.z; s1[7] = (_Float16)v3.w;
        *(f16x8*)&Xs[sr][sk] = s0;
        *(f16x8*)&Xs[sr][sk + 8] = s1;
        __syncthreads();

        const int k0 = q * 8;
        f16x8 a0 = *(const f16x8*)&Xs[(w * 2 + 0) * 16 + m][k0];
        f16x8 a1 = *(const f16x8*)&Xs[(w * 2 + 1) * 16 + m][k0];
        const int kw = kc * 32 + k0;
#pragma unroll
        for (int ct = 0; ct < 8; ++ct) {
            f16x8 b = *(const f16x8*)&Wt[ct * 16 + m][kw];
            acc[0][ct] = __builtin_amdgcn_mfma_f32_16x16x32_f16(a0, b, acc[0][ct], 0, 0, 0);
            acc[1][ct] = __builtin_amdgcn_mfma_f32_16x16x32_f16(a1, b, acc[1][ct], 0, 0, 0);
        }
    }

#pragma unroll
    for (int rt = 0; rt < 2; ++rt)
#pragma unroll
        for (int ct = 0; ct < 8; ++ct)
#pragma unroll
            for (int r = 0; r < 4; ++r) {
                int row = r0 + (w * 2 + rt) * 16 + q * 4 + r;
                if (row < M)
                    C[(size_t)row * 128 + ct * 16 + m] = (half_t)acc[rt][ct][r];
            }
}

// ---------------- k1: gemm1 blocks, then pass-A binning blocks --------------

__launch_bounds__(256)
__global__ void gemm_binA_k(const float* __restrict__ A, const float* __restrict__ W,
                            half_t* __restrict__ C, int M, int Gg1,
                            const int* __restrict__ esrc, const int* __restrict__ edst,
                            int* __restrict__ bucket_cnt, unsigned int* __restrict__ ebuf,
                            int E) {
    int b = blockIdx.x;
    if (b < Gg1) {
        gemm1_mfma(A, W, C, M, b * 128);
        return;
    }
    __shared__ int cntA[256];
    __shared__ int curA[256];
    __shared__ int deltaA[256];
    __shared__ int wsumA[4];

    const int t = threadIdx.x;
    const int base = (b - Gg1) * 4096;
    int ls[16], ld[16];

    cntA[t] = 0;
    __syncthreads();
#pragma unroll
    for (int j = 0; j < 16; ++j) {
        int idx = base + j * 256 + t;
        if (idx < E) {
            ls[j] = esrc[idx];
            ld[j] = edst[idx];
            atomicAdd(&cntA[ld[j] >> 8], 1);
        } else {
            ls[j] = -1;
            ld[j] = 0;
        }
    }
    __syncthreads();

    int c = cntA[t];
    int incl = incl_scan256(c, wsumA);      // contains a __syncthreads
    int excl = incl - c;
    int gbase = atomicAdd(&bucket_cnt[t], c);       // offset within bucket segment
    deltaA[t] = t * BKT_CAP + gbase - excl;         // absolute = seg base + offset
    curA[t] = excl;
    __syncthreads();

#pragma unroll
    for (int j = 0; j < 16; ++j) {
        if (ls[j] >= 0) {
            int bkt = ld[j] >> 8;
            int p = atomicAdd(&curA[bkt], 1);
            ebuf[deltaA[bkt] + p] = ((unsigned int)ls[j] << 8) | ((unsigned int)ld[j] & 255u);
        }
    }
}

// ---------------- k2 (pass B): counting sort -> rs/dinv/ssrc, + hs1 scale ---
// Sort key = ((dst&255)<<3) | (src>>13): per-node adjacency grouped by
// 8192-node source tile (R18 ordering). Tail: scale this bucket's 256 hs1
// rows in-place by dinv (folds the old scale_k into this kernel).

__launch_bounds__(256)
__global__ void binB_k(const int* __restrict__ bucket_cnt,
                       const unsigned int* __restrict__ ebuf,
                       unsigned short* __restrict__ ssrc,
                       int* __restrict__ rs, float* __restrict__ dinv,
                       half_t* __restrict__ hs1,
                       int N, int NB) {
    __shared__ int cnt[2048];                  // per (dstlow, tile) counters
    __shared__ int pre[256];
    __shared__ float dinvs[256];               // this bucket's dinv (for scale tail)
    __shared__ int wsum1[4];
    __shared__ int wsum2[4];

    const int t = threadIdx.x;
    const int b = blockIdx.x;

    int v = (t < NB) ? bucket_cnt[t] : 0;
    int inclb = incl_scan256(v, wsum1);
    pre[t] = inclb;
    __syncthreads();
    const int gb = (b > 0) ? pre[b - 1] : 0;
    const int sz = pre[b] - gb;
    const unsigned int* seg = ebuf + (size_t)b * BKT_CAP;

#pragma unroll
    for (int i = 0; i < 8; ++i) cnt[t + i * 256] = 0;
    __syncthreads();
    for (int i = t; i < sz; i += 256) {
        unsigned int pk = seg[i];
        int key = ((pk & 255u) << 3) | ((pk >> 8) >> 13);   // (dstlow, srctile)
        atomicAdd(&cnt[key], 1);
    }
    __syncthreads();

    // thread t owns keys 8t..8t+7 (= node dstlow t, all 8 tiles)
    int c8[8];
    int s = 0;
#pragma unroll
    for (int j = 0; j < 8; ++j) { c8[j] = cnt[t * 8 + j]; s += c8[j]; }
    int incl = incl_scan256(s, wsum2);         // contains a __syncthreads
    int excl = incl - s;
    int node = b * 256 + t;
    float dval = rsqrtf(1.0f + (float)s);
    dinvs[t] = dval;
    if (node < N) {
        rs[node] = gb + excl;
        dinv[node] = dval;
    }
    int run = excl;
#pragma unroll
    for (int j = 0; j < 8; ++j) { int cv = c8[j]; cnt[t * 8 + j] = run; run += cv; }
    __syncthreads();

    for (int i = t; i < sz; i += 256) {
        unsigned int pk = seg[i];
        int key = ((pk & 255u) << 3) | ((pk >> 8) >> 13);
        int p = atomicAdd(&cnt[key], 1);
        ssrc[gb + p] = (unsigned short)(pk >> 8);
    }

    // tail: scale this bucket's hs1 rows in-place.
    // Wave w covers 64 rows in 8 batches of 8; all 8 row-loads of a batch
    // are hoisted -> 8 outstanding loads/wave (R22 had unroll(1) serial
    // load->store = 64 x ~600cy exposed latency = the +16us regression).
    {
        const int w = t >> 6, lane = t & 63;
#pragma unroll 1
        for (int i = 0; i < 8; ++i) {
            const int rbase = i * 32 + w * 8;
            half2_t v8[8];
            int rows[8];
#pragma unroll
            for (int j = 0; j < 8; ++j) {
                int row = b * 256 + rbase + j;
                rows[j] = row;
                if (row < N)
                    v8[j] = *(const half2_t*)&hs1[(size_t)row * 128 + 2 * lane];
            }
#pragma unroll
            for (int j = 0; j < 8; ++j) {
                if (rows[j] < N) {
                    float sc = dinvs[rbase + j];
                    half2_t hv = v8[j];
                    hv.x = (half_t)((float)hv.x * sc);
                    hv.y = (half_t)((float)hv.y * sc);
                    *(half2_t*)&hs1[(size_t)rows[j] * 128 + 2 * lane] = hv;
                }
            }
        }
    }
}

// ---------------- g1mm: fused gather1 (quarter-wave/node) + gemm2 -----------
// hs rows pre-scaled by dinv (binB tail), so the aggregate is a pure sum:
// g1_row = relu(dv * (sum_in hs[s] + hs[node]) + b1).
// Per block: 16 nodes; each wave owns 4 concurrent nodes (one per 16-lane
// quarter, f16x8/lane = 128 dims). Rows -> LDS g1s, then M=16 MFMA with
// W2^T; epilogue scales by dinv (pre-scaling hs2 for gather2).

__launch_bounds__(256)
__global__ void g1mm_k(const half_t* __restrict__ hs,
                       const unsigned short* __restrict__ ssrc,
                       const int* __restrict__ rs,
                       const float* __restrict__ dinv,
                       const float* __restrict__ b1,
                       const float* __restrict__ W2,
                       half_t* __restrict__ o, int N, int E) {
    __shared__ _Float16 Wt[64][136];           // [n][k], W2^T fp16
    __shared__ _Float16 g1s[16][136];          // gathered+activated rows
    const int t = threadIdx.x;

    // stage W2^T fp16: coalesced reads along n, b64 writes along k
    {
        const int n = t & 63;
#pragma unroll
        for (int kb = (t >> 6) * 4; kb < 128; kb += 16) {
            f16x4 hv;
            hv[0] = (_Float16)W2[(size_t)(kb + 0) * 64 + n];
            hv[1] = (_Float16)W2[(size_t)(kb + 1) * 64 + n];
            hv[2] = (_Float16)W2[(size_t)(kb + 2) * 64 + n];
            hv[3] = (_Float16)W2[(size_t)(kb + 3) * 64 + n];
            *(f16x4*)&Wt[n][kb] = hv;
        }
    }

    const int w = t >> 6, lane = t & 63;
    const int qd = lane >> 4, l4 = lane & 15;
    const int nb = blockIdx.x * 16;
    const half_t* hp = hs + 8 * l4;            // dims 8*l4 .. 8*l4+7
    const int sl = qd * 16;                    // shfl base for this quarter

    int node = nb + w * 4 + qd;                // this quarter's node
    int vnode = (node < N) ? node : (N - 1);
    int start = rs[vnode];
    int end = (vnode + 1 < N) ? rs[vnode + 1] : E;
    float dv = dinv[vnode];

    f16x8 sv = *(const f16x8*)&hp[(size_t)vnode * 128];   // self (pre-scaled)
    float acc[8];
#pragma unroll
    for (int j = 0; j < 8; ++j) acc[j] = (float)sv[j];

    for (int base = start; base < end; base += 16) {
        int n = end - base;
        if (n > 16) n = 16;
        int gi = (base + l4 < end) ? (base + l4) : base;
        int idx = (int)ssrc[gi];
        int e = 0;
        for (; e + 4 <= n; e += 4) {           // 4 edges in flight per quarter
            int s0 = __shfl(idx, sl + e + 0);
            int s1 = __shfl(idx, sl + e + 1);
            int s2 = __shfl(idx, sl + e + 2);
            int s3 = __shfl(idx, sl + e + 3);
            f16x8 x0 = *(const f16x8*)&hp[(size_t)s0 * 128];
            f16x8 x1 = *(const f16x8*)&hp[(size_t)s1 * 128];
            f16x8 x2 = *(const f16x8*)&hp[(size_t)s2 * 128];
            f16x8 x3 = *(const f16x8*)&hp[(size_t)s3 * 128];
#pragma unroll
            for (int j = 0; j < 8; ++j) acc[j] += (float)x0[j];
#pragma unroll
            for (int j = 0; j < 8; ++j) acc[j] += (float)x1[j];
#pragma unroll
            for (int j = 0; j < 8; ++j) acc[j] += (float)x2[j];
#pragma unroll
            for (int j = 0; j < 8; ++j) acc[j] += (float)x3[j];
        }
        for (; e < n; ++e) {
            int s0 = __shfl(idx, sl + e);
            f16x8 x0 = *(const f16x8*)&hp[(size_t)s0 * 128];
#pragma unroll
            for (int j = 0; j < 8; ++j) acc[j] += (float)x0[j];
        }
    }

    // epilogue: relu(acc*dv + b1) -> LDS row (each quarter owns a full row)
    {
        float4 ba = *(const float4*)&b1[8 * l4];
        float4 bb = *(const float4*)&b1[8 * l4 + 4];
        f16x8 hv;
        hv[0] = (half_t)fmaxf(acc[0] * dv + ba.x, 0.f);
        hv[1] = (half_t)fmaxf(acc[1] * dv + ba.y, 0.f);
        hv[2] = (half_t)fmaxf(acc[2] * dv + ba.z, 0.f);
        hv[3] = (half_t)fmaxf(acc[3] * dv + ba.w, 0.f);
        hv[4] = (half_t)fmaxf(acc[4] * dv + bb.x, 0.f);
        hv[5] = (half_t)fmaxf(acc[5] * dv + bb.y, 0.f);
        hv[6] = (half_t)fmaxf(acc[6] * dv + bb.z, 0.f);
        hv[7] = (half_t)fmaxf(acc[7] * dv + bb.w, 0.f);
        *(f16x8*)&g1s[w * 4 + qd][8 * l4] = hv;
    }
    __syncthreads();

    // M=16 x N=64 x K=128 MFMA; wave w owns output cols w*16..w*16+15
    const int m = lane & 15, q = lane >> 4;
    f32x4 acc2;
#pragma unroll
    for (int r = 0; r < 4; ++r) acc2[r] = 0.f;
#pragma unroll
    for (int kc = 0; kc < 4; ++kc) {
        const int k0 = kc * 32 + q * 8;
        f16x8 a = *(const f16x8*)&g1s[m][k0];
        f16x8 b = *(const f16x8*)&Wt[w * 16 + m][k0];
        acc2 = __builtin_amdgcn_mfma_f32_16x16x32_f16(a, b, acc2, 0, 0, 0);
    }
#pragma unroll
    for (int r = 0; r < 4; ++r) {
        int row = nb + q * 4 + r;
        if (row < N) {
            float s = dinv[row];
            o[(size_t)row * 64 + w * 16 + m] = (half_t)(acc2[r] * s);
        }
    }
}

// ---------------- gather2: 64-dim, eighth-wave per node, fp32 out -----------

__global__ void gather2_k(const half_t* __restrict__ hs,
                          const unsigned short* __restrict__ ssrc,
                          const int* __restrict__ rs,
                          const float* __restrict__ dinv,
                          const float* __restrict__ bias,
                          float* __restrict__ o, int N, int E) {
    int wid = (int)((blockIdx.x * blockDim.x + threadIdx.x) >> 6);
    int lane = threadIdx.x & 63;
    const int sg = lane >> 3, l3 = lane & 7;
    int rnode = wid * 8 + sg;                  // this eighth's node
    int node = (rnode < N) ? rnode : (N - 1);

    int start = rs[node];
    int end = (node + 1 < N) ? rs[node + 1] : E;
    float dv = dinv[node];
    const int sl = sg * 8;

    const half_t* hp = hs + 8 * l3;            // dims 8*l3 .. 8*l3+7
    f16x8 sv = *(const f16x8*)&hp[(size_t)node * 64];
    float acc[8];
#pragma unroll
    for (int j = 0; j < 8; ++j) acc[j] = (float)sv[j];   // self (pre-scaled)

    for (int base = start; base < end; base += 8) {
        int n = end - base;
        if (n > 8) n = 8;
        int gi = (base + l3 < end) ? (base + l3) : base;
        int idx = (int)ssrc[gi];
        int e = 0;
        for (; e + 4 <= n; e += 4) {           // 4 edges in flight per eighth
            int s0 = __shfl(idx, sl + e + 0);
            int s1 = __shfl(idx, sl + e + 1);
            int s2 = __shfl(idx, sl + e + 2);
            int s3 = __shfl(idx, sl + e + 3);
            f16x8 a0 = *(const f16x8*)&hp[(size_t)s0 * 64];
            f16x8 a1 = *(const f16x8*)&hp[(size_t)s1 * 64];
            f16x8 a2 = *(const f16x8*)&hp[(size_t)s2 * 64];
            f16x8 a3 = *(const f16x8*)&hp[(size_t)s3 * 64];
#pragma unroll
            for (int j = 0; j < 8; ++j) acc[j] += (float)a0[j];
#pragma unroll
            for (int j = 0; j < 8; ++j) acc[j] += (float)a1[j];
#pragma unroll
            for (int j = 0; j < 8; ++j) acc[j] += (float)a2[j];
#pragma unroll
            for (int j = 0; j < 8; ++j) acc[j] += (float)a3[j];
        }
        for (; e < n; ++e) {
            int s0 = __shfl(idx, sl + e);
            f16x8 a0 = *(const f16x8*)&hp[(size_t)s0 * 64];
#pragma unroll
            for (int j = 0; j < 8; ++j) acc[j] += (float)a0[j];
        }
    }
    if (rnode < N) {
        float4 b0 = *(const float4*)&bias[8 * l3];
        float4 b1v = *(const float4*)&bias[8 * l3 + 4];
        float4 o0, o1;
        o0.x = acc[0] * dv + b0.x;
        o0.y = acc[1] * dv + b0.y;
        o0.z = acc[2] * dv + b0.z;
        o0.w = acc[3] * dv + b0.w;
        o1.x = acc[4] * dv + b1v.x;
        o1.y = acc[5] * dv + b1v.y;
        o1.z = acc[6] * dv + b1v.z;
        o1.w = acc[7] * dv + b1v.w;
        *(float4*)&o[(size_t)rnode * 64 + 8 * l3] = o0;
        *(float4*)&o[(size_t)rnode * 64 + 8 * l3 + 4] = o1;
    }
}

// ---------------- launcher ----------------

extern "C" void kernel_launch(void* const* d_in, const int* in_sizes, int n_in,
                              void* d_out, int out_size, void* d_ws, size_t ws_size,
                              hipStream_t stream) {
    const float* x  = (const float*)d_in[0];
    const int*   ei = (const int*)d_in[1];
    const float* W1 = (const float*)d_in[2];
    const float* b1 = (const float*)d_in[3];
    const float* W2 = (const float*)d_in[4];
    const float* b2 = (const float*)d_in[5];
    float* out = (float*)d_out;

    const int N = in_sizes[0] / 128;
    const int E = in_sizes[1] / 2;
    const int* esrc = ei;
    const int* edst = ei + E;

    const int NB  = (N + 255) / 256;          // buckets (<=256 requires N<=65536)
    const int Gg1 = (N + 127) / 128;
    const int GA  = (E + 4095) / 4096;

    // workspace layout
    int* bucket_cnt = (int*)d_ws;                             // 256
    unsigned int* ebuf = (unsigned int*)(bucket_cnt + 256);   // NB*BKT_CAP packed edges
    unsigned short* ssrc = (unsigned short*)(ebuf + (size_t)NB * BKT_CAP); // E uint16
    int* rs = (int*)(ssrc + ((E + 1) & ~1));                  // N
    float* dinv = (float*)(rs + N);                           // N
    half_t* hs1 = (half_t*)(dinv + N);                        // N*128 fp16 (scaled in binB)
    half_t* hs2 = hs1 + (size_t)N * 128;                      // N*64 fp16 (pre-scaled)

    hipMemsetAsync(bucket_cnt, 0, 256 * 4, stream);

    // k1: gemm1 (unscaled fp16 h1) ∪ pass-A edge binning
    hipLaunchKernelGGL(gemm_binA_k, dim3(Gg1 + GA), dim3(256), 0, stream,
                       x, W1, hs1, N, Gg1, esrc, edst, bucket_cnt, ebuf, E);
    // k2: counting sort (dst, src-tile) -> rs, dinv, ssrc; + hs1 *= dinv tail
    hipLaunchKernelGGL(binB_k, dim3(NB), dim3(256), 0, stream,
                       bucket_cnt, ebuf, ssrc, rs, dinv, hs1, N, NB);
    // fused layer-1 aggregate + layer-2 linear (writes pre-scaled hs2)
    hipLaunchKernelGGL(g1mm_k, dim3((N + 15) / 16), dim3(256), 0, stream,
                       hs1, ssrc, rs, dinv, b1, W2, hs2, N, E);
    // layer-2 aggregate
    hipLaunchKernelGGL(gather2_k, dim3((N + 31) / 32), dim3(256), 0, stream,
                       hs2, ssrc, rs, dinv, b2, out, N, E);
}

// Round 11
// 165.330 us; speedup vs baseline: 1.0766x; 1.0325x over previous
//
#include <hip/hip_runtime.h>
#include <hip/hip_fp16.h>

// GCN 2-layer, pull-based CSR gather, fp16 dense intermediates.
// R24: reorder to kill scale_k's 25.6MB without folding (R22/R23 showed the
// fold starves the scale of parallelism on binB's critical path):
//   binA -> binB -> gemm1(x dinv epilogue) -> g1mm -> gather2
// gemm1 now runs AFTER the sort, so its epilogue multiplies each row by
// dinv[row] (from binB) and hs1 is written once, already scaled - no scale
// pass, no extra fp16 rounding. Cost: binA no longer overlaps gemm1 (~3us).
// Launch count unchanged (5). binB/g1mm/gather2 byte-identical to R18
// (best verified, 161.8us). N <= 65536.

typedef _Float16 half_t;
typedef _Float16 half2_t __attribute__((ext_vector_type(2)));
typedef _Float16 f16x4 __attribute__((ext_vector_type(4)));
typedef _Float16 f16x8 __attribute__((ext_vector_type(8)));
typedef float f32x4 __attribute__((ext_vector_type(4)));

#define BKT_CAP 8192   // per-bucket ebuf capacity (expected load 4096, sigma 64)

// inclusive block scan over 256 threads (4 waves); caller provides 4-int LDS
__device__ __forceinline__ int incl_scan256(int v, volatile int* wsum) {
    int t = threadIdx.x, lane = t & 63, w = t >> 6;
#pragma unroll
    for (int off = 1; off < 64; off <<= 1) {
        int u = __shfl_up(v, off);
        if (lane >= off) v += u;
    }
    if (lane == 63) wsum[w] = v;
    __syncthreads();
    int add = 0;
#pragma unroll
    for (int i = 0; i < 3; ++i)
        if (i < w) add += wsum[i];
    return v + add;
}

// ---------------- binA: bucket edges into ebuf (standalone) -----------------

__launch_bounds__(256)
__global__ void binA_k(const int* __restrict__ esrc, const int* __restrict__ edst,
                       int* __restrict__ bucket_cnt, unsigned int* __restrict__ ebuf,
                       int E) {
    __shared__ int cntA[256];
    __shared__ int curA[256];
    __shared__ int deltaA[256];
    __shared__ int wsumA[4];

    const int t = threadIdx.x;
    const int base = blockIdx.x * 4096;
    int ls[16], ld[16];

    cntA[t] = 0;
    __syncthreads();
#pragma unroll
    for (int j = 0; j < 16; ++j) {
        int idx = base + j * 256 + t;
        if (idx < E) {
            ls[j] = esrc[idx];
            ld[j] = edst[idx];
            atomicAdd(&cntA[ld[j] >> 8], 1);
        } else {
            ls[j] = -1;
            ld[j] = 0;
        }
    }
    __syncthreads();

    int c = cntA[t];
    int incl = incl_scan256(c, wsumA);      // contains a __syncthreads
    int excl = incl - c;
    int gbase = atomicAdd(&bucket_cnt[t], c);       // offset within bucket segment
    deltaA[t] = t * BKT_CAP + gbase - excl;         // absolute = seg base + offset
    curA[t] = excl;
    __syncthreads();

#pragma unroll
    for (int j = 0; j < 16; ++j) {
        if (ls[j] >= 0) {
            int bkt = ld[j] >> 8;
            int p = atomicAdd(&curA[bkt], 1);
            ebuf[deltaA[bkt] + p] = ((unsigned int)ls[j] << 8) | ((unsigned int)ld[j] & 255u);
        }
    }
}

// ---------------- binB: per-bucket counting sort -> rs/dinv/ssrc ------------
// Sort key = ((dst&255)<<3) | (src>>13): per-node adjacency grouped by
// 8192-node source tile (R18 ordering).

__launch_bounds__(256)
__global__ void binB_k(const int* __restrict__ bucket_cnt,
                       const unsigned int* __restrict__ ebuf,
                       unsigned short* __restrict__ ssrc,
                       int* __restrict__ rs, float* __restrict__ dinv,
                       int N, int NB) {
    __shared__ int cnt[2048];                  // per (dstlow, tile) counters
    __shared__ int pre[256];
    __shared__ int wsum1[4];
    __shared__ int wsum2[4];

    const int t = threadIdx.x;
    const int b = blockIdx.x;

    int v = (t < NB) ? bucket_cnt[t] : 0;
    int inclb = incl_scan256(v, wsum1);
    pre[t] = inclb;
    __syncthreads();
    const int gb = (b > 0) ? pre[b - 1] : 0;
    const int sz = pre[b] - gb;
    const unsigned int* seg = ebuf + (size_t)b * BKT_CAP;

#pragma unroll
    for (int i = 0; i < 8; ++i) cnt[t + i * 256] = 0;
    __syncthreads();
    for (int i = t; i < sz; i += 256) {
        unsigned int pk = seg[i];
        int key = ((pk & 255u) << 3) | ((pk >> 8) >> 13);   // (dstlow, srctile)
        atomicAdd(&cnt[key], 1);
    }
    __syncthreads();

    // thread t owns keys 8t..8t+7 (= node dstlow t, all 8 tiles)
    int c8[8];
    int s = 0;
#pragma unroll
    for (int j = 0; j < 8; ++j) { c8[j] = cnt[t * 8 + j]; s += c8[j]; }
    int incl = incl_scan256(s, wsum2);         // contains a __syncthreads
    int excl = incl - s;
    int node = b * 256 + t;
    if (node < N) {
        rs[node] = gb + excl;
        dinv[node] = rsqrtf(1.0f + (float)s);
    }
    int run = excl;
#pragma unroll
    for (int j = 0; j < 8; ++j) { int cv = c8[j]; cnt[t * 8 + j] = run; run += cv; }
    __syncthreads();

    for (int i = t; i < sz; i += 256) {
        unsigned int pk = seg[i];
        int key = ((pk & 255u) << 3) | ((pk >> 8) >> 13);
        int p = atomicAdd(&cnt[key], 1);
        ssrc[gb + p] = (unsigned short)(pk >> 8);
    }
}

// ---------------- gemm1: 128x128 tile via f16 MFMA, dinv-scaled epilogue ----
// MFMA 16x16x32 layouts (gfx950, HW-verified):
//   A-frag: lane holds A[m=lane&15][k=(lane>>4)*8+j]
//   B-frag: lane holds B[k=(lane>>4)*8+j][n=lane&15]
//   C/D   : col=lane&15, row=(lane>>4)*4+reg
// Runs after binB: epilogue multiplies row by dinv[row], so hs1 is written
// once, already scaled (gathers are then pure unweighted sums).

__launch_bounds__(256)
__global__ void gemm1_k(const float* __restrict__ x,
                        const float* __restrict__ W,
                        const float* __restrict__ dinv,
                        half_t* __restrict__ C, int M) {
    __shared__ _Float16 Wt[128][136];          // [n][k], rows 272B (b128-aligned)
    __shared__ _Float16 Xs[128][40];           // [m][k-chunk], rows 80B
    const int t = threadIdx.x;
    const int r0 = blockIdx.x * 128;

    // stage W^T fp16: coalesced reads along n, b64 writes along k
    {
        const int n = t & 127;
#pragma unroll
        for (int kb = (t >> 7) * 4; kb < 128; kb += 8) {
            f16x4 hv;
            hv[0] = (_Float16)W[(size_t)(kb + 0) * 128 + n];
            hv[1] = (_Float16)W[(size_t)(kb + 1) * 128 + n];
            hv[2] = (_Float16)W[(size_t)(kb + 2) * 128 + n];
            hv[3] = (_Float16)W[(size_t)(kb + 3) * 128 + n];
            *(f16x4*)&Wt[n][kb] = hv;
        }
    }

    const int w = t >> 6, lane = t & 63;
    const int m = lane & 15, q = lane >> 4;

    // Xs staging coords: 16 floats (one row-half-chunk) per thread per kc
    const int sr = t >> 1;               // 0..127 tile row
    const int sk = (t & 1) * 16;         // 0 or 16 within 32-k chunk
    const int srow = (r0 + sr < M) ? (r0 + sr) : (M - 1);

    f32x4 acc[2][8];
#pragma unroll
    for (int rt = 0; rt < 2; ++rt)
#pragma unroll
        for (int ct = 0; ct < 8; ++ct)
#pragma unroll
            for (int r = 0; r < 4; ++r) acc[rt][ct][r] = 0.f;

#pragma unroll
    for (int kc = 0; kc < 4; ++kc) {
        // coalesced global loads issued before the barrier (overlap prev MFMAs)
        const float* xp = &x[(size_t)srow * 128 + kc * 32 + sk];
        float4 v0 = *(const float4*)xp;
        float4 v1 = *(const float4*)(xp + 4);
        float4 v2 = *(const float4*)(xp + 8);
        float4 v3 = *(const float4*)(xp + 12);
        __syncthreads();                 // prev iter's Xs reads done (&& Wt staged)
        f16x8 s0, s1;
        s0[0] = (_Float16)v0.x; s0[1] = (_Float16)v0.y;
        s0[2] = (_Float16)v0.z; s0[3] = (_Float16)v0.w;
        s0[4] = (_Float16)v1.x; s0[5] = (_Float16)v1.y;
        s0[6] = (_Float16)v1.z; s0[7] = (_Float16)v1.w;
        s1[0] = (_Float16)v2.x; s1[1] = (_Float16)v2.y;
        s1[2] = (_Float16)v2.z; s1[3] = (_Float16)v2.w;
        s1[4] = (_Float16)v3.x; s1[5] = (_Float16)v3.y;
        s1[6] = (_Float16)v3.z; s1[7] = (_Float16)v3.w;
        *(f16x8*)&Xs[sr][sk] = s0;
        *(f16x8*)&Xs[sr][sk + 8] = s1;
        __syncthreads();

        const int k0 = q * 8;
        f16x8 a0 = *(const f16x8*)&Xs[(w * 2 + 0) * 16 + m][k0];
        f16x8 a1 = *(const f16x8*)&Xs[(w * 2 + 1) * 16 + m][k0];
        const int kw = kc * 32 + k0;
#pragma unroll
        for (int ct = 0; ct < 8; ++ct) {
            f16x8 b = *(const f16x8*)&Wt[ct * 16 + m][kw];
            acc[0][ct] = __builtin_amdgcn_mfma_f32_16x16x32_f16(a0, b, acc[0][ct], 0, 0, 0);
            acc[1][ct] = __builtin_amdgcn_mfma_f32_16x16x32_f16(a1, b, acc[1][ct], 0, 0, 0);
        }
    }

#pragma unroll
    for (int rt = 0; rt < 2; ++rt)
#pragma unroll
        for (int r = 0; r < 4; ++r) {
            int row = r0 + (w * 2 + rt) * 16 + q * 4 + r;
            if (row < M) {
                float s = dinv[row];
#pragma unroll
                for (int ct = 0; ct < 8; ++ct)
                    C[(size_t)row * 128 + ct * 16 + m] = (half_t)(acc[rt][ct][r] * s);
            }
        }
}

// ---------------- g1mm: fused gather1 (quarter-wave/node) + gemm2 -----------
// hs rows pre-scaled by dinv (gemm1 epilogue), so the aggregate is a pure
// sum: g1_row = relu(dv * (sum_in hs[s] + hs[node]) + b1).
// Per block: 16 nodes; each wave owns 4 concurrent nodes (one per 16-lane
// quarter, f16x8/lane = 128 dims). Rows -> LDS g1s, then M=16 MFMA with
// W2^T; epilogue scales by dinv (pre-scaling hs2 for gather2).

__launch_bounds__(256)
__global__ void g1mm_k(const half_t* __restrict__ hs,
                       const unsigned short* __restrict__ ssrc,
                       const int* __restrict__ rs,
                       const float* __restrict__ dinv,
                       const float* __restrict__ b1,
                       const float* __restrict__ W2,
                       half_t* __restrict__ o, int N, int E) {
    __shared__ _Float16 Wt[64][136];           // [n][k], W2^T fp16
    __shared__ _Float16 g1s[16][136];          // gathered+activated rows
    const int t = threadIdx.x;

    // stage W2^T fp16: coalesced reads along n, b64 writes along k
    {
        const int n = t & 63;
#pragma unroll
        for (int kb = (t >> 6) * 4; kb < 128; kb += 16) {
            f16x4 hv;
            hv[0] = (_Float16)W2[(size_t)(kb + 0) * 64 + n];
            hv[1] = (_Float16)W2[(size_t)(kb + 1) * 64 + n];
            hv[2] = (_Float16)W2[(size_t)(kb + 2) * 64 + n];
            hv[3] = (_Float16)W2[(size_t)(kb + 3) * 64 + n];
            *(f16x4*)&Wt[n][kb] = hv;
        }
    }

    const int w = t >> 6, lane = t & 63;
    const int qd = lane >> 4, l4 = lane & 15;
    const int nb = blockIdx.x * 16;
    const half_t* hp = hs + 8 * l4;            // dims 8*l4 .. 8*l4+7
    const int sl = qd * 16;                    // shfl base for this quarter

    int node = nb + w * 4 + qd;                // this quarter's node
    int vnode = (node < N) ? node : (N - 1);
    int start = rs[vnode];
    int end = (vnode + 1 < N) ? rs[vnode + 1] : E;
    float dv = dinv[vnode];

    f16x8 sv = *(const f16x8*)&hp[(size_t)vnode * 128];   // self (pre-scaled)
    float acc[8];
#pragma unroll
    for (int j = 0; j < 8; ++j) acc[j] = (float)sv[j];

    for (int base = start; base < end; base += 16) {
        int n = end - base;
        if (n > 16) n = 16;
        int gi = (base + l4 < end) ? (base + l4) : base;
        int idx = (int)ssrc[gi];
        int e = 0;
        for (; e + 4 <= n; e += 4) {           // 4 edges in flight per quarter
            int s0 = __shfl(idx, sl + e + 0);
            int s1 = __shfl(idx, sl + e + 1);
            int s2 = __shfl(idx, sl + e + 2);
            int s3 = __shfl(idx, sl + e + 3);
            f16x8 x0 = *(const f16x8*)&hp[(size_t)s0 * 128];
            f16x8 x1 = *(const f16x8*)&hp[(size_t)s1 * 128];
            f16x8 x2 = *(const f16x8*)&hp[(size_t)s2 * 128];
            f16x8 x3 = *(const f16x8*)&hp[(size_t)s3 * 128];
#pragma unroll
            for (int j = 0; j < 8; ++j) acc[j] += (float)x0[j];
#pragma unroll
            for (int j = 0; j < 8; ++j) acc[j] += (float)x1[j];
#pragma unroll
            for (int j = 0; j < 8; ++j) acc[j] += (float)x2[j];
#pragma unroll
            for (int j = 0; j < 8; ++j) acc[j] += (float)x3[j];
        }
        for (; e < n; ++e) {
            int s0 = __shfl(idx, sl + e);
            f16x8 x0 = *(const f16x8*)&hp[(size_t)s0 * 128];
#pragma unroll
            for (int j = 0; j < 8; ++j) acc[j] += (float)x0[j];
        }
    }

    // epilogue: relu(acc*dv + b1) -> LDS row (each quarter owns a full row)
    {
        float4 ba = *(const float4*)&b1[8 * l4];
        float4 bb = *(const float4*)&b1[8 * l4 + 4];
        f16x8 hv;
        hv[0] = (half_t)fmaxf(acc[0] * dv + ba.x, 0.f);
        hv[1] = (half_t)fmaxf(acc[1] * dv + ba.y, 0.f);
        hv[2] = (half_t)fmaxf(acc[2] * dv + ba.z, 0.f);
        hv[3] = (half_t)fmaxf(acc[3] * dv + ba.w, 0.f);
        hv[4] = (half_t)fmaxf(acc[4] * dv + bb.x, 0.f);
        hv[5] = (half_t)fmaxf(acc[5] * dv + bb.y, 0.f);
        hv[6] = (half_t)fmaxf(acc[6] * dv + bb.z, 0.f);
        hv[7] = (half_t)fmaxf(acc[7] * dv + bb.w, 0.f);
        *(f16x8*)&g1s[w * 4 + qd][8 * l4] = hv;
    }
    __syncthreads();

    // M=16 x N=64 x K=128 MFMA; wave w owns output cols w*16..w*16+15
    const int m = lane & 15, q = lane >> 4;
    f32x4 acc2;
#pragma unroll
    for (int r = 0; r < 4; ++r) acc2[r] = 0.f;
#pragma unroll
    for (int kc = 0; kc < 4; ++kc) {
        const int k0 = kc * 32 + q * 8;
        f16x8 a = *(const f16x8*)&g1s[m][k0];
        f16x8 b = *(const f16x8*)&Wt[w * 16 + m][k0];
        acc2 = __builtin_amdgcn_mfma_f32_16x16x32_f16(a, b, acc2, 0, 0, 0);
    }
#pragma unroll
    for (int r = 0; r < 4; ++r) {
        int row = nb + q * 4 + r;
        if (row < N) {
            float s = dinv[row];
            o[(size_t)row * 64 + w * 16 + m] = (half_t)(acc2[r] * s);
        }
    }
}

// ---------------- gather2: 64-dim, eighth-wave per node, fp32 out -----------

__global__ void gather2_k(const half_t* __restrict__ hs,
                          const unsigned short* __restrict__ ssrc,
                          const int* __restrict__ rs,
                          const float* __restrict__ dinv,
                          const float* __restrict__ bias,
                          float* __restrict__ o, int N, int E) {
    int wid = (int)((blockIdx.x * blockDim.x + threadIdx.x) >> 6);
    int lane = threadIdx.x & 63;
    const int sg = lane >> 3, l3 = lane & 7;
    int rnode = wid * 8 + sg;                  // this eighth's node
    int node = (rnode < N) ? rnode : (N - 1);

    int start = rs[node];
    int end = (node + 1 < N) ? rs[node + 1] : E;
    float dv = dinv[node];
    const int sl = sg * 8;

    const half_t* hp = hs + 8 * l3;            // dims 8*l3 .. 8*l3+7
    f16x8 sv = *(const f16x8*)&hp[(size_t)node * 64];
    float acc[8];
#pragma unroll
    for (int j = 0; j < 8; ++j) acc[j] = (float)sv[j];   // self (pre-scaled)

    for (int base = start; base < end; base += 8) {
        int n = end - base;
        if (n > 8) n = 8;
        int gi = (base + l3 < end) ? (base + l3) : base;
        int idx = (int)ssrc[gi];
        int e = 0;
        for (; e + 4 <= n; e += 4) {           // 4 edges in flight per eighth
            int s0 = __shfl(idx, sl + e + 0);
            int s1 = __shfl(idx, sl + e + 1);
            int s2 = __shfl(idx, sl + e + 2);
            int s3 = __shfl(idx, sl + e + 3);
            f16x8 a0 = *(const f16x8*)&hp[(size_t)s0 * 64];
            f16x8 a1 = *(const f16x8*)&hp[(size_t)s1 * 64];
            f16x8 a2 = *(const f16x8*)&hp[(size_t)s2 * 64];
            f16x8 a3 = *(const f16x8*)&hp[(size_t)s3 * 64];
#pragma unroll
            for (int j = 0; j < 8; ++j) acc[j] += (float)a0[j];
#pragma unroll
            for (int j = 0; j < 8; ++j) acc[j] += (float)a1[j];
#pragma unroll
            for (int j = 0; j < 8; ++j) acc[j] += (float)a2[j];
#pragma unroll
            for (int j = 0; j < 8; ++j) acc[j] += (float)a3[j];
        }
        for (; e < n; ++e) {
            int s0 = __shfl(idx, sl + e);
            f16x8 a0 = *(const f16x8*)&hp[(size_t)s0 * 64];
#pragma unroll
            for (int j = 0; j < 8; ++j) acc[j] += (float)a0[j];
        }
    }
    if (rnode < N) {
        float4 b0 = *(const float4*)&bias[8 * l3];
        float4 b1v = *(const float4*)&bias[8 * l3 + 4];
        float4 o0, o1;
        o0.x = acc[0] * dv + b0.x;
        o0.y = acc[1] * dv + b0.y;
        o0.z = acc[2] * dv + b0.z;
        o0.w = acc[3] * dv + b0.w;
        o1.x = acc[4] * dv + b1v.x;
        o1.y = acc[5] * dv + b1v.y;
        o1.z = acc[6] * dv + b1v.z;
        o1.w = acc[7] * dv + b1v.w;
        *(float4*)&o[(size_t)rnode * 64 + 8 * l3] = o0;
        *(float4*)&o[(size_t)rnode * 64 + 8 * l3 + 4] = o1;
    }
}

// ---------------- launcher ----------------

extern "C" void kernel_launch(void* const* d_in, const int* in_sizes, int n_in,
                              void* d_out, int out_size, void* d_ws, size_t ws_size,
                              hipStream_t stream) {
    const float* x  = (const float*)d_in[0];
    const int*   ei = (const int*)d_in[1];
    const float* W1 = (const float*)d_in[2];
    const float* b1 = (const float*)d_in[3];
    const float* W2 = (const float*)d_in[4];
    const float* b2 = (const float*)d_in[5];
    float* out = (float*)d_out;

    const int N = in_sizes[0] / 128;
    const int E = in_sizes[1] / 2;
    const int* esrc = ei;
    const int* edst = ei + E;

    const int NB  = (N + 255) / 256;          // buckets (<=256 requires N<=65536)
    const int Gg1 = (N + 127) / 128;
    const int GA  = (E + 4095) / 4096;

    // workspace layout
    int* bucket_cnt = (int*)d_ws;                             // 256
    unsigned int* ebuf = (unsigned int*)(bucket_cnt + 256);   // NB*BKT_CAP packed edges
    unsigned short* ssrc = (unsigned short*)(ebuf + (size_t)NB * BKT_CAP); // E uint16
    int* rs = (int*)(ssrc + ((E + 1) & ~1));                  // N
    float* dinv = (float*)(rs + N);                           // N
    half_t* hs1 = (half_t*)(dinv + N);                        // N*128 fp16 (pre-scaled)
    half_t* hs2 = hs1 + (size_t)N * 128;                      // N*64 fp16 (pre-scaled)

    hipMemsetAsync(bucket_cnt, 0, 256 * 4, stream);

    // k1: pass-A edge binning
    hipLaunchKernelGGL(binA_k, dim3(GA), dim3(256), 0, stream,
                       esrc, edst, bucket_cnt, ebuf, E);
    // k2: counting sort (dst, src-tile) -> rs, dinv, ssrc
    hipLaunchKernelGGL(binB_k, dim3(NB), dim3(256), 0, stream,
                       bucket_cnt, ebuf, ssrc, rs, dinv, N, NB);
    // k3: gemm1 with dinv-scaled epilogue -> hs1 (written once, scaled)
    hipLaunchKernelGGL(gemm1_k, dim3(Gg1), dim3(256), 0, stream,
                       x, W1, dinv, hs1, N);
    // k4: fused layer-1 aggregate + layer-2 linear (writes pre-scaled hs2)
    hipLaunchKernelGGL(g1mm_k, dim3((N + 15) / 16), dim3(256), 0, stream,
                       hs1, ssrc, rs, dinv, b1, W2, hs2, N, E);
    // k5: layer-2 aggregate
    hipLaunchKernelGGL(gather2_k, dim3((N + 31) / 32), dim3(256), 0, stream,
                       hs2, ssrc, rs, dinv, b2, out, N, E);
}

// Round 12
// 163.600 us; speedup vs baseline: 1.0880x; 1.0106x over previous
//
#include <hip/hip_runtime.h>
#include <hip/hip_fp16.h>

// GCN 2-layer, pull-based CSR gather, fp16 dense intermediates.
// R25 = exact revert to R18 (best verified: 161.8us). Session final.
// Structure: k1 = gemm1 ∪ binA (bin blocks overlap behind gemm MFMA blocks),
// binB = 2048-key (dst, src-tile) counting sort -> rs/dinv/ssrc, scale_k
// (hs1 *= dinv, wide 12.5k-block pass), g1mm = quarter-wave-per-node
// gather1 + M=16 MFMA gemm2, gather2 = eighth-wave-per-node.
// Variants tried and rejected (R19-R24, all >= R18): cooperative fusion
// (crash: VGPR occupancy < co-residency), 64-dim panel split (+7: double
// edge processing), scale fold into binB (+16/+9: starved of parallelism
// on sort critical path), binA->binB->gemm1 reorder (+3.5: lost binA
// overlap). N <= 65536.

typedef _Float16 half_t;
typedef _Float16 half2_t __attribute__((ext_vector_type(2)));
typedef _Float16 f16x4 __attribute__((ext_vector_type(4)));
typedef _Float16 f16x8 __attribute__((ext_vector_type(8)));
typedef float f32x4 __attribute__((ext_vector_type(4)));

#define BKT_CAP 8192   // per-bucket ebuf capacity (expected load 4096, sigma 64)

// inclusive block scan over 256 threads (4 waves); caller provides 4-int LDS
__device__ __forceinline__ int incl_scan256(int v, volatile int* wsum) {
    int t = threadIdx.x, lane = t & 63, w = t >> 6;
#pragma unroll
    for (int off = 1; off < 64; off <<= 1) {
        int u = __shfl_up(v, off);
        if (lane >= off) v += u;
    }
    if (lane == 63) wsum[w] = v;
    __syncthreads();
    int add = 0;
#pragma unroll
    for (int i = 0; i < 3; ++i)
        if (i < w) add += wsum[i];
    return v + add;
}

// ---------------- gemm1: 128x128 tile via f16 MFMA ----------------
// MFMA 16x16x32 layouts (gfx950, HW-verified):
//   A-frag: lane holds A[m=lane&15][k=(lane>>4)*8+j]
//   B-frag: lane holds B[k=(lane>>4)*8+j][n=lane&15]
//   C/D   : col=lane&15, row=(lane>>4)*4+reg

__device__ __forceinline__ void gemm1_mfma(const float* __restrict__ x,
                                           const float* __restrict__ W,
                                           half_t* __restrict__ C, int M, int r0) {
    __shared__ _Float16 Wt[128][136];          // [n][k], rows 272B (b128-aligned)
    __shared__ _Float16 Xs[128][40];           // [m][k-chunk], rows 80B
    const int t = threadIdx.x;

    // stage W^T fp16: coalesced reads along n, b64 writes along k
    {
        const int n = t & 127;
#pragma unroll
        for (int kb = (t >> 7) * 4; kb < 128; kb += 8) {
            f16x4 hv;
            hv[0] = (_Float16)W[(size_t)(kb + 0) * 128 + n];
            hv[1] = (_Float16)W[(size_t)(kb + 1) * 128 + n];
            hv[2] = (_Float16)W[(size_t)(kb + 2) * 128 + n];
            hv[3] = (_Float16)W[(size_t)(kb + 3) * 128 + n];
            *(f16x4*)&Wt[n][kb] = hv;
        }
    }

    const int w = t >> 6, lane = t & 63;
    const int m = lane & 15, q = lane >> 4;

    // Xs staging coords: 16 floats (one row-half-chunk) per thread per kc
    const int sr = t >> 1;               // 0..127 tile row
    const int sk = (t & 1) * 16;         // 0 or 16 within 32-k chunk
    const int srow = (r0 + sr < M) ? (r0 + sr) : (M - 1);

    f32x4 acc[2][8];
#pragma unroll
    for (int rt = 0; rt < 2; ++rt)
#pragma unroll
        for (int ct = 0; ct < 8; ++ct)
#pragma unroll
            for (int r = 0; r < 4; ++r) acc[rt][ct][r] = 0.f;

#pragma unroll
    for (int kc = 0; kc < 4; ++kc) {
        // coalesced global loads issued before the barrier (overlap prev MFMAs)
        const float* xp = &x[(size_t)srow * 128 + kc * 32 + sk];
        float4 v0 = *(const float4*)xp;
        float4 v1 = *(const float4*)(xp + 4);
        float4 v2 = *(const float4*)(xp + 8);
        float4 v3 = *(const float4*)(xp + 12);
        __syncthreads();                 // prev iter's Xs reads done (&& Wt staged)
        f16x8 s0, s1;
        s0[0] = (_Float16)v0.x; s0[1] = (_Float16)v0.y;
        s0[2] = (_Float16)v0.z; s0[3] = (_Float16)v0.w;
        s0[4] = (_Float16)v1.x; s0[5] = (_Float16)v1.y;
        s0[6] = (_Float16)v1.z; s0[7] = (_Float16)v1.w;
        s1[0] = (_Float16)v2.x; s1[1] = (_Float16)v2.y;
        s1[2] = (_Float16)v2.z; s1[3] = (_Float16)v2.w;
        s1[4] = (_Float16)v3.x; s1[5] = (_Float16)v3.y;
        s1[6] = (_Float16)v3.z; s1[7] = (_Float16)v3.w;
        *(f16x8*)&Xs[sr][sk] = s0;
        *(f16x8*)&Xs[sr][sk + 8] = s1;
        __syncthreads();

        const int k0 = q * 8;
        f16x8 a0 = *(const f16x8*)&Xs[(w * 2 + 0) * 16 + m][k0];
        f16x8 a1 = *(const f16x8*)&Xs[(w * 2 + 1) * 16 + m][k0];
        const int kw = kc * 32 + k0;
#pragma unroll
        for (int ct = 0; ct < 8; ++ct) {
            f16x8 b = *(const f16x8*)&Wt[ct * 16 + m][kw];
            acc[0][ct] = __builtin_amdgcn_mfma_f32_16x16x32_f16(a0, b, acc[0][ct], 0, 0, 0);
            acc[1][ct] = __builtin_amdgcn_mfma_f32_16x16x32_f16(a1, b, acc[1][ct], 0, 0, 0);
        }
    }

#pragma unroll
    for (int rt = 0; rt < 2; ++rt)
#pragma unroll
        for (int ct = 0; ct < 8; ++ct)
#pragma unroll
            for (int r = 0; r < 4; ++r) {
                int row = r0 + (w * 2 + rt) * 16 + q * 4 + r;
                if (row < M)
                    C[(size_t)row * 128 + ct * 16 + m] = (half_t)acc[rt][ct][r];
            }
}

// ---------------- k1: gemm1 blocks, then pass-A binning blocks --------------

__launch_bounds__(256)
__global__ void gemm_binA_k(const float* __restrict__ A, const float* __restrict__ W,
                            half_t* __restrict__ C, int M, int Gg1,
                            const int* __restrict__ esrc, const int* __restrict__ edst,
                            int* __restrict__ bucket_cnt, unsigned int* __restrict__ ebuf,
                            int E) {
    int b = blockIdx.x;
    if (b < Gg1) {
        gemm1_mfma(A, W, C, M, b * 128);
        return;
    }
    __shared__ int cntA[256];
    __shared__ int curA[256];
    __shared__ int deltaA[256];
    __shared__ int wsumA[4];

    const int t = threadIdx.x;
    const int base = (b - Gg1) * 4096;
    int ls[16], ld[16];

    cntA[t] = 0;
    __syncthreads();
#pragma unroll
    for (int j = 0; j < 16; ++j) {
        int idx = base + j * 256 + t;
        if (idx < E) {
            ls[j] = esrc[idx];
            ld[j] = edst[idx];
            atomicAdd(&cntA[ld[j] >> 8], 1);
        } else {
            ls[j] = -1;
            ld[j] = 0;
        }
    }
    __syncthreads();

    int c = cntA[t];
    int incl = incl_scan256(c, wsumA);      // contains a __syncthreads
    int excl = incl - c;
    int gbase = atomicAdd(&bucket_cnt[t], c);       // offset within bucket segment
    deltaA[t] = t * BKT_CAP + gbase - excl;         // absolute = seg base + offset
    curA[t] = excl;
    __syncthreads();

#pragma unroll
    for (int j = 0; j < 16; ++j) {
        if (ls[j] >= 0) {
            int bkt = ld[j] >> 8;
            int p = atomicAdd(&curA[bkt], 1);
            ebuf[deltaA[bkt] + p] = ((unsigned int)ls[j] << 8) | ((unsigned int)ld[j] & 255u);
        }
    }
}

// ---------------- k2 (pass B): per-bucket counting sort -> rs/dinv/ssrc -----
// Sort key = ((dst&255)<<3) | (src>>13): per-node adjacency grouped by
// 8192-node source tile (2 MB hs1 slab -> L2-resident during its phase).

__launch_bounds__(256)
__global__ void binB_k(const int* __restrict__ bucket_cnt,
                       const unsigned int* __restrict__ ebuf,
                       unsigned short* __restrict__ ssrc,
                       int* __restrict__ rs, float* __restrict__ dinv,
                       int N, int NB) {
    __shared__ int cnt[2048];                  // per (dstlow, tile) counters
    __shared__ int pre[256];
    __shared__ int wsum1[4];
    __shared__ int wsum2[4];

    const int t = threadIdx.x;
    const int b = blockIdx.x;

    int v = (t < NB) ? bucket_cnt[t] : 0;
    int inclb = incl_scan256(v, wsum1);
    pre[t] = inclb;
    __syncthreads();
    const int gb = (b > 0) ? pre[b - 1] : 0;
    const int sz = pre[b] - gb;
    const unsigned int* seg = ebuf + (size_t)b * BKT_CAP;

#pragma unroll
    for (int i = 0; i < 8; ++i) cnt[t + i * 256] = 0;
    __syncthreads();
    for (int i = t; i < sz; i += 256) {
        unsigned int pk = seg[i];
        int key = ((pk & 255u) << 3) | ((pk >> 8) >> 13);   // (dstlow, srctile)
        atomicAdd(&cnt[key], 1);
    }
    __syncthreads();

    // thread t owns keys 8t..8t+7 (= node dstlow t, all 8 tiles)
    int c8[8];
    int s = 0;
#pragma unroll
    for (int j = 0; j < 8; ++j) { c8[j] = cnt[t * 8 + j]; s += c8[j]; }
    int incl = incl_scan256(s, wsum2);         // contains a __syncthreads
    int excl = incl - s;
    int node = b * 256 + t;
    if (node < N) {
        rs[node] = gb + excl;
        dinv[node] = rsqrtf(1.0f + (float)s);
    }
    int run = excl;
#pragma unroll
    for (int j = 0; j < 8; ++j) { int cv = c8[j]; cnt[t * 8 + j] = run; run += cv; }
    __syncthreads();

    for (int i = t; i < sz; i += 256) {
        unsigned int pk = seg[i];
        int key = ((pk & 255u) << 3) | ((pk >> 8) >> 13);
        int p = atomicAdd(&cnt[key], 1);
        ssrc[gb + p] = (unsigned short)(pk >> 8);
    }
}

// ---------------- scale_k: hs1[row] *= dinv[row] (wave per node) ------------

__global__ void scale_k(half_t* __restrict__ hs, const float* __restrict__ dinv, int N) {
    int node = (int)((blockIdx.x * blockDim.x + threadIdx.x) >> 6);
    int lane = threadIdx.x & 63;
    if (node >= N) return;
    float s = dinv[node];
    half2_t* p = (half2_t*)&hs[(size_t)node * 128 + 2 * lane];
    half2_t v = *p;
    v.x = (half_t)((float)v.x * s);
    v.y = (half_t)((float)v.y * s);
    *p = v;
}

// ---------------- g1mm: fused gather1 (quarter-wave/node) + gemm2 -----------
// hs rows pre-scaled by dinv (scale_k), so the aggregate is a pure sum:
// g1_row = relu(dv * (sum_in hs[s] + hs[node]) + b1).
// Per block: 16 nodes; each wave owns 4 concurrent nodes (one per 16-lane
// quarter, f16x8/lane = 128 dims). Rows -> LDS g1s, then M=16 MFMA with
// W2^T; epilogue scales by dinv (pre-scaling hs2 for gather2).

__launch_bounds__(256)
__global__ void g1mm_k(const half_t* __restrict__ hs,
                       const unsigned short* __restrict__ ssrc,
                       const int* __restrict__ rs,
                       const float* __restrict__ dinv,
                       const float* __restrict__ b1,
                       const float* __restrict__ W2,
                       half_t* __restrict__ o, int N, int E) {
    __shared__ _Float16 Wt[64][136];           // [n][k], W2^T fp16
    __shared__ _Float16 g1s[16][136];          // gathered+activated rows
    const int t = threadIdx.x;

    // stage W2^T fp16: coalesced reads along n, b64 writes along k
    {
        const int n = t & 63;
#pragma unroll
        for (int kb = (t >> 6) * 4; kb < 128; kb += 16) {
            f16x4 hv;
            hv[0] = (_Float16)W2[(size_t)(kb + 0) * 64 + n];
            hv[1] = (_Float16)W2[(size_t)(kb + 1) * 64 + n];
            hv[2] = (_Float16)W2[(size_t)(kb + 2) * 64 + n];
            hv[3] = (_Float16)W2[(size_t)(kb + 3) * 64 + n];
            *(f16x4*)&Wt[n][kb] = hv;
        }
    }

    const int w = t >> 6, lane = t & 63;
    const int qd = lane >> 4, l4 = lane & 15;
    const int nb = blockIdx.x * 16;
    const half_t* hp = hs + 8 * l4;            // dims 8*l4 .. 8*l4+7
    const int sl = qd * 16;                    // shfl base for this quarter

    int node = nb + w * 4 + qd;                // this quarter's node
    int vnode = (node < N) ? node : (N - 1);
    int start = rs[vnode];
    int end = (vnode + 1 < N) ? rs[vnode + 1] : E;
    float dv = dinv[vnode];

    f16x8 sv = *(const f16x8*)&hp[(size_t)vnode * 128];   // self (pre-scaled)
    float acc[8];
#pragma unroll
    for (int j = 0; j < 8; ++j) acc[j] = (float)sv[j];

    for (int base = start; base < end; base += 16) {
        int n = end - base;
        if (n > 16) n = 16;
        int gi = (base + l4 < end) ? (base + l4) : base;
        int idx = (int)ssrc[gi];
        int e = 0;
        for (; e + 4 <= n; e += 4) {           // 4 edges in flight per quarter
            int s0 = __shfl(idx, sl + e + 0);
            int s1 = __shfl(idx, sl + e + 1);
            int s2 = __shfl(idx, sl + e + 2);
            int s3 = __shfl(idx, sl + e + 3);
            f16x8 x0 = *(const f16x8*)&hp[(size_t)s0 * 128];
            f16x8 x1 = *(const f16x8*)&hp[(size_t)s1 * 128];
            f16x8 x2 = *(const f16x8*)&hp[(size_t)s2 * 128];
            f16x8 x3 = *(const f16x8*)&hp[(size_t)s3 * 128];
#pragma unroll
            for (int j = 0; j < 8; ++j) acc[j] += (float)x0[j];
#pragma unroll
            for (int j = 0; j < 8; ++j) acc[j] += (float)x1[j];
#pragma unroll
            for (int j = 0; j < 8; ++j) acc[j] += (float)x2[j];
#pragma unroll
            for (int j = 0; j < 8; ++j) acc[j] += (float)x3[j];
        }
        for (; e < n; ++e) {
            int s0 = __shfl(idx, sl + e);
            f16x8 x0 = *(const f16x8*)&hp[(size_t)s0 * 128];
#pragma unroll
            for (int j = 0; j < 8; ++j) acc[j] += (float)x0[j];
        }
    }

    // epilogue: relu(acc*dv + b1) -> LDS row (each quarter owns a full row)
    {
        float4 ba = *(const float4*)&b1[8 * l4];
        float4 bb = *(const float4*)&b1[8 * l4 + 4];
        f16x8 hv;
        hv[0] = (half_t)fmaxf(acc[0] * dv + ba.x, 0.f);
        hv[1] = (half_t)fmaxf(acc[1] * dv + ba.y, 0.f);
        hv[2] = (half_t)fmaxf(acc[2] * dv + ba.z, 0.f);
        hv[3] = (half_t)fmaxf(acc[3] * dv + ba.w, 0.f);
        hv[4] = (half_t)fmaxf(acc[4] * dv + bb.x, 0.f);
        hv[5] = (half_t)fmaxf(acc[5] * dv + bb.y, 0.f);
        hv[6] = (half_t)fmaxf(acc[6] * dv + bb.z, 0.f);
        hv[7] = (half_t)fmaxf(acc[7] * dv + bb.w, 0.f);
        *(f16x8*)&g1s[w * 4 + qd][8 * l4] = hv;
    }
    __syncthreads();

    // M=16 x N=64 x K=128 MFMA; wave w owns output cols w*16..w*16+15
    const int m = lane & 15, q = lane >> 4;
    f32x4 acc2;
#pragma unroll
    for (int r = 0; r < 4; ++r) acc2[r] = 0.f;
#pragma unroll
    for (int kc = 0; kc < 4; ++kc) {
        const int k0 = kc * 32 + q * 8;
        f16x8 a = *(const f16x8*)&g1s[m][k0];
        f16x8 b = *(const f16x8*)&Wt[w * 16 + m][k0];
        acc2 = __builtin_amdgcn_mfma_f32_16x16x32_f16(a, b, acc2, 0, 0, 0);
    }
#pragma unroll
    for (int r = 0; r < 4; ++r) {
        int row = nb + q * 4 + r;
        if (row < N) {
            float s = dinv[row];
            o[(size_t)row * 64 + w * 16 + m] = (half_t)(acc2[r] * s);
        }
    }
}

// ---------------- gather2: 64-dim, eighth-wave per node, fp32 out -----------

__global__ void gather2_k(const half_t* __restrict__ hs,
                          const unsigned short* __restrict__ ssrc,
                          const int* __restrict__ rs,
                          const float* __restrict__ dinv,
                          const float* __restrict__ bias,
                          float* __restrict__ o, int N, int E) {
    int wid = (int)((blockIdx.x * blockDim.x + threadIdx.x) >> 6);
    int lane = threadIdx.x & 63;
    const int sg = lane >> 3, l3 = lane & 7;
    int rnode = wid * 8 + sg;                  // this eighth's node
    int node = (rnode < N) ? rnode : (N - 1);

    int start = rs[node];
    int end = (node + 1 < N) ? rs[node + 1] : E;
    float dv = dinv[node];
    const int sl = sg * 8;

    const half_t* hp = hs + 8 * l3;            // dims 8*l3 .. 8*l3+7
    f16x8 sv = *(const f16x8*)&hp[(size_t)node * 64];
    float acc[8];
#pragma unroll
    for (int j = 0; j < 8; ++j) acc[j] = (float)sv[j];   // self (pre-scaled)

    for (int base = start; base < end; base += 8) {
        int n = end - base;
        if (n > 8) n = 8;
        int gi = (base + l3 < end) ? (base + l3) : base;
        int idx = (int)ssrc[gi];
        int e = 0;
        for (; e + 4 <= n; e += 4) {           // 4 edges in flight per eighth
            int s0 = __shfl(idx, sl + e + 0);
            int s1 = __shfl(idx, sl + e + 1);
            int s2 = __shfl(idx, sl + e + 2);
            int s3 = __shfl(idx, sl + e + 3);
            f16x8 a0 = *(const f16x8*)&hp[(size_t)s0 * 64];
            f16x8 a1 = *(const f16x8*)&hp[(size_t)s1 * 64];
            f16x8 a2 = *(const f16x8*)&hp[(size_t)s2 * 64];
            f16x8 a3 = *(const f16x8*)&hp[(size_t)s3 * 64];
#pragma unroll
            for (int j = 0; j < 8; ++j) acc[j] += (float)a0[j];
#pragma unroll
            for (int j = 0; j < 8; ++j) acc[j] += (float)a1[j];
#pragma unroll
            for (int j = 0; j < 8; ++j) acc[j] += (float)a2[j];
#pragma unroll
            for (int j = 0; j < 8; ++j) acc[j] += (float)a3[j];
        }
        for (; e < n; ++e) {
            int s0 = __shfl(idx, sl + e);
            f16x8 a0 = *(const f16x8*)&hp[(size_t)s0 * 64];
#pragma unroll
            for (int j = 0; j < 8; ++j) acc[j] += (float)a0[j];
        }
    }
    if (rnode < N) {
        float4 b0 = *(const float4*)&bias[8 * l3];
        float4 b1v = *(const float4*)&bias[8 * l3 + 4];
        float4 o0, o1;
        o0.x = acc[0] * dv + b0.x;
        o0.y = acc[1] * dv + b0.y;
        o0.z = acc[2] * dv + b0.z;
        o0.w = acc[3] * dv + b0.w;
        o1.x = acc[4] * dv + b1v.x;
        o1.y = acc[5] * dv + b1v.y;
        o1.z = acc[6] * dv + b1v.z;
        o1.w = acc[7] * dv + b1v.w;
        *(float4*)&o[(size_t)rnode * 64 + 8 * l3] = o0;
        *(float4*)&o[(size_t)rnode * 64 + 8 * l3 + 4] = o1;
    }
}

// ---------------- launcher ----------------

extern "C" void kernel_launch(void* const* d_in, const int* in_sizes, int n_in,
                              void* d_out, int out_size, void* d_ws, size_t ws_size,
                              hipStream_t stream) {
    const float* x  = (const float*)d_in[0];
    const int*   ei = (const int*)d_in[1];
    const float* W1 = (const float*)d_in[2];
    const float* b1 = (const float*)d_in[3];
    const float* W2 = (const float*)d_in[4];
    const float* b2 = (const float*)d_in[5];
    float* out = (float*)d_out;

    const int N = in_sizes[0] / 128;
    const int E = in_sizes[1] / 2;
    const int* esrc = ei;
    const int* edst = ei + E;

    const int NB  = (N + 255) / 256;          // buckets (<=256 requires N<=65536)
    const int Gg1 = (N + 127) / 128;
    const int GA  = (E + 4095) / 4096;

    // workspace layout
    int* bucket_cnt = (int*)d_ws;                             // 256
    unsigned int* ebuf = (unsigned int*)(bucket_cnt + 256);   // NB*BKT_CAP packed edges
    unsigned short* ssrc = (unsigned short*)(ebuf + (size_t)NB * BKT_CAP); // E uint16
    int* rs = (int*)(ssrc + ((E + 1) & ~1));                  // N
    float* dinv = (float*)(rs + N);                           // N
    half_t* hs1 = (half_t*)(dinv + N);                        // N*128 fp16 (scaled in-place)
    half_t* hs2 = hs1 + (size_t)N * 128;                      // N*64 fp16 (pre-scaled)

    hipMemsetAsync(bucket_cnt, 0, 256 * 4, stream);

    // k1: gemm1 (unscaled fp16 h1) ∪ pass-A edge binning
    hipLaunchKernelGGL(gemm_binA_k, dim3(Gg1 + GA), dim3(256), 0, stream,
                       x, W1, hs1, N, Gg1, esrc, edst, bucket_cnt, ebuf, E);
    // k2: per-bucket counting sort (dst, src-tile) -> rs, dinv, ssrc
    hipLaunchKernelGGL(binB_k, dim3(NB), dim3(256), 0, stream,
                       bucket_cnt, ebuf, ssrc, rs, dinv, N, NB);
    // k2.5: pre-scale hs1 rows by dinv (makes gather1 a pure sum)
    hipLaunchKernelGGL(scale_k, dim3((N + 3) / 4), dim3(256), 0, stream,
                       hs1, dinv, N);
    // fused layer-1 aggregate + layer-2 linear (writes pre-scaled hs2)
    hipLaunchKernelGGL(g1mm_k, dim3((N + 15) / 16), dim3(256), 0, stream,
                       hs1, ssrc, rs, dinv, b1, W2, hs2, N, E);
    // layer-2 aggregate
    hipLaunchKernelGGL(gather2_k, dim3((N + 31) / 32), dim3(256), 0, stream,
                       hs2, ssrc, rs, dinv, b2, out, N, E);
}